// Round 7
// baseline (519.279 us; speedup 1.0000x reference)
//
#include <hip/hip_runtime.h>
#include <hip/hip_cooperative_groups.h>

namespace cg = cooperative_groups;

#define T_TOK 2048
#define DM    512
#define DFF   512
#define NE    16
#define LDK   72   // padded LDS row stride (ushorts): 144 B rotates banks by 4/row

typedef __attribute__((ext_vector_type(8))) short bf16x8;
typedef __attribute__((ext_vector_type(4))) float f32x4;
typedef __attribute__((ext_vector_type(8))) unsigned short us8;

__device__ __forceinline__ unsigned short f2bf(float f) {
  unsigned int u = __float_as_uint(f);
  u += 0x7fffu + ((u >> 16) & 1u);   // round-to-nearest-even
  return (unsigned short)(u >> 16);
}

#define MFMA(a,b,c) __builtin_amdgcn_mfma_f32_16x16x32_bf16((a),(b),(c),0,0,0)

// phases: mode==0 all phases with grid sync (cooperative); mode 1..5 single phase
__global__ __launch_bounds__(256, 4) void moe_kernel(
    const float* __restrict__ x,   const float* __restrict__ gw,
    const float* __restrict__ bias,
    const float* __restrict__ sgu, const float* __restrict__ sdn,
    const float* __restrict__ egu, const float* __restrict__ edn,
    int* __restrict__ counts, int* __restrict__ list,
    float* __restrict__ wgt,  int* __restrict__ tokslot,
    unsigned short* __restrict__ xb,   unsigned short* __restrict__ sgub,
    unsigned short* __restrict__ sdnb, unsigned short* __restrict__ egub,
    unsigned short* __restrict__ ednb,
    unsigned short* __restrict__ Hall, float* __restrict__ ro,
    float* __restrict__ out, int mode)
{
  cg::grid_group gg = cg::this_grid();
  __shared__ unsigned short SA[64][LDK];
  __shared__ unsigned short SB[64][LDK];
  __shared__ unsigned short SC[64][LDK];
  __shared__ float lg[4][16];
  __shared__ int bcnt[16], bbase[16];
  __shared__ int sel_s[4][3], pos_s[4][3];
  __shared__ float g_s[4][3];
  __shared__ int rbase[16];

  const int tid  = threadIdx.x;
  const int nb   = gridDim.x;
  const int gtid = blockIdx.x * 256 + tid;
  const int T    = nb * 256;

  // ================= Phase A: zero counts + fp32->bf16 convert =============
  if (mode == 0 || mode == 1) {
    if (gtid < 16) counts[gtid] = 0;
    // groups of 8 elems: x 131072 | sgu 65536 | sdn 32768 | egu 1048576 | edn 524288
    for (int g = gtid; g < 1802240; g += T) {
      const float* s; unsigned short* d; int l;
      if      (g <  131072) { s = x;   d = xb;   l = g;           }
      else if (g <  196608) { s = sgu; d = sgub; l = g -  131072; }
      else if (g <  229376) { s = sdn; d = sdnb; l = g -  196608; }
      else if (g < 1277952) { s = egu; d = egub; l = g -  229376; }
      else                  { s = edn; d = ednb; l = g - 1277952; }
      const float* p = s + (size_t)l * 8;
      float4 v0 = *(const float4*)p;
      float4 v1 = *(const float4*)(p + 4);
      us8 o;
      o[0]=f2bf(v0.x); o[1]=f2bf(v0.y); o[2]=f2bf(v0.z); o[3]=f2bf(v0.w);
      o[4]=f2bf(v1.x); o[5]=f2bf(v1.y); o[6]=f2bf(v1.z); o[7]=f2bf(v1.w);
      *(us8*)(d + (size_t)l * 8) = o;
    }
  }
  if (mode == 0) gg.sync();

  // ================= Phase B: router (one token per wave) ===================
  if (mode == 0 || mode == 2) {
    for (int ru = blockIdx.x; ru < 512; ru += nb) {
      const int w = tid >> 6, lane = tid & 63;
      if (tid < 16) bcnt[tid] = 0;
      const int tok = ru * 4 + w;
      const int e = lane & 15, part = lane >> 4;

      const float* xr = x + (size_t)tok * DM + part * 128;
      const float* wr = gw + (size_t)e * DM + part * 128;
      float acc = 0.f;
      #pragma unroll 8
      for (int i = 0; i < 128; i += 4) {
        float4 xv = *(const float4*)(xr + i);
        float4 wv = *(const float4*)(wr + i);
        acc += xv.x*wv.x + xv.y*wv.y + xv.z*wv.z + xv.w*wv.w;
      }
      acc += __shfl_xor(acc, 16);
      acc += __shfl_xor(acc, 32);
      if (lane < 16) lg[w][lane] = 1.f / (1.f + __expf(-acc));  // affinity
      __syncthreads();

      if (tid < 4) {
        float aff[16], sc[16];
        #pragma unroll
        for (int i = 0; i < 16; ++i) { aff[i] = lg[tid][i]; sc[i] = aff[i] + bias[i]; }
        int sel[3]; float sa[3]; float sum = 0.f;
        #pragma unroll
        for (int k = 0; k < 3; ++k) {
          float best = -1e30f; int bi = 0;
          for (int i = 0; i < 16; ++i) {
            bool used = false;
            for (int j = 0; j < k; ++j) used |= (sel[j] == i);
            if (!used && sc[i] > best) { best = sc[i]; bi = i; }
          }
          sel[k] = bi; sa[k] = aff[bi]; sum += aff[bi];
        }
        float inv = 1.f / (sum + 1e-9f);
        #pragma unroll
        for (int k = 0; k < 3; ++k) {
          int p = atomicAdd(&bcnt[sel[k]], 1);
          sel_s[tid][k] = sel[k]; pos_s[tid][k] = p; g_s[tid][k] = sa[k] * inv;
        }
      }
      __syncthreads();
      if (tid < 16) bbase[tid] = atomicAdd(&counts[tid], bcnt[tid]);
      __syncthreads();
      if (tid < 4) {
        #pragma unroll
        for (int k = 0; k < 3; ++k) {
          int E = sel_s[tid][k];
          int p = bbase[E] + pos_s[tid][k];
          int t = ru * 4 + tid;
          list[E * T_TOK + p]  = t;
          wgt [E * T_TOK + p]  = g_s[tid][k];
          tokslot[t * 3 + k]   = (E << 16) | p;
        }
      }
      __syncthreads();
    }
  }
  if (mode == 0) gg.sync();

  // ================= Phase C: GEMM1 (x @ Wgu^T, silu*up -> Hall) ===========
  if (mode == 0 || mode == 3) {
    for (int u = blockIdx.x; u < 17 * 256; u += nb) {
      const int z = u >> 8, rem = u & 255, mt = rem >> 3, n0 = (rem & 7) * 64;
      int cnt, hb; const unsigned short* W;
      if (z == 0) { cnt = T_TOK; hb = 0; W = sgub; }
      else {
        cnt = counts[z - 1];
        if (mt * 64 >= cnt) continue;
        hb = T_TOK;
        for (int i = 0; i < z - 1; ++i) hb += counts[i];
        W = egub + (size_t)(z - 1) * (2 * DFF * DM);
      }

      const int sr = tid >> 2, sc = (tid & 3) * 16;
      const int entry = mt * 64 + sr;
      const bool avalid = entry < cnt;
      const unsigned short* arow = xb;
      if (avalid) {
        const int tok = (z == 0) ? entry : list[(z - 1) * T_TOK + entry];
        arow = xb + (size_t)tok * DM;
      }
      const unsigned short* grow = W + (size_t)(n0 + sr) * DM;
      const unsigned short* urow = W + (size_t)(DFF + n0 + sr) * DM;

      const int lane = tid & 63;
      const int wm = ((tid >> 6) & 1) * 32;
      const int wn = ((tid >> 7) & 1) * 32;
      const int lr = lane & 15, qd = lane >> 4;

      const f32x4 z4 = {0.f, 0.f, 0.f, 0.f};
      f32x4 accg[2][2], accu[2][2];
      #pragma unroll
      for (int i = 0; i < 2; ++i)
        #pragma unroll
        for (int j = 0; j < 2; ++j) { accg[i][j] = z4; accu[i][j] = z4; }

      for (int k0 = 0; k0 < DM; k0 += 64) {
        us8 av0 = {0,0,0,0,0,0,0,0}, av1 = {0,0,0,0,0,0,0,0};
        if (avalid) {
          av0 = *(const us8*)(arow + k0 + sc);
          av1 = *(const us8*)(arow + k0 + sc + 8);
        }
        us8 gv0 = *(const us8*)(grow + k0 + sc);
        us8 gv1 = *(const us8*)(grow + k0 + sc + 8);
        us8 uv0 = *(const us8*)(urow + k0 + sc);
        us8 uv1 = *(const us8*)(urow + k0 + sc + 8);
        __syncthreads();
        *(us8*)&SA[sr][sc] = av0; *(us8*)&SA[sr][sc + 8] = av1;
        *(us8*)&SB[sr][sc] = gv0; *(us8*)&SB[sr][sc + 8] = gv1;
        *(us8*)&SC[sr][sc] = uv0; *(us8*)&SC[sr][sc + 8] = uv1;
        __syncthreads();
        #pragma unroll
        for (int ks = 0; ks < 2; ++ks) {
          const int kk = ks * 32 + qd * 8;
          bf16x8 a0 = *(const bf16x8*)&SA[wm      + lr][kk];
          bf16x8 a1 = *(const bf16x8*)&SA[wm + 16 + lr][kk];
          bf16x8 g0 = *(const bf16x8*)&SB[wn      + lr][kk];
          bf16x8 g1 = *(const bf16x8*)&SB[wn + 16 + lr][kk];
          bf16x8 u0 = *(const bf16x8*)&SC[wn      + lr][kk];
          bf16x8 u1 = *(const bf16x8*)&SC[wn + 16 + lr][kk];
          accg[0][0] = MFMA(a0, g0, accg[0][0]);
          accg[0][1] = MFMA(a0, g1, accg[0][1]);
          accg[1][0] = MFMA(a1, g0, accg[1][0]);
          accg[1][1] = MFMA(a1, g1, accg[1][1]);
          accu[0][0] = MFMA(a0, u0, accu[0][0]);
          accu[0][1] = MFMA(a0, u1, accu[0][1]);
          accu[1][0] = MFMA(a1, u0, accu[1][0]);
          accu[1][1] = MFMA(a1, u1, accu[1][1]);
        }
      }

      #pragma unroll
      for (int sm = 0; sm < 2; ++sm)
        #pragma unroll
        for (int sn = 0; sn < 2; ++sn) {
          const int col = n0 + wn + sn * 16 + lr;
          #pragma unroll
          for (int r = 0; r < 4; ++r) {
            const int ent = mt * 64 + wm + sm * 16 + qd * 4 + r;
            if (ent < cnt) {
              float g = accg[sm][sn][r];
              float uv = accu[sm][sn][r];
              float h = (g / (1.f + __expf(-g))) * uv;   // silu(g)*u
              Hall[(size_t)(hb + ent) * DFF + col] = f2bf(h);
            }
          }
        }
      __syncthreads();
    }
  }
  if (mode == 0) gg.sync();

  // ================= Phase D: GEMM2 (H @ Wd^T -> out / ro) =================
  if (mode == 0 || mode == 4) {
    for (int u = blockIdx.x; u < 17 * 256; u += nb) {
      const int z = u >> 8, rem = u & 255, mt = rem >> 3, n0 = (rem & 7) * 64;
      int cnt, hb; const unsigned short* W;
      if (z == 0) { cnt = T_TOK; hb = 0; W = sdnb; }
      else {
        cnt = counts[z - 1];
        if (mt * 64 >= cnt) continue;
        hb = T_TOK;
        for (int i = 0; i < z - 1; ++i) hb += counts[i];
        W = ednb + (size_t)(z - 1) * (DM * DFF);
      }
      const int rb = hb - T_TOK;   // routed compact base (z>0)

      const int sr = tid >> 2, sc = (tid & 3) * 16;
      const int entry = mt * 64 + sr;
      const bool avalid = entry < cnt;
      const unsigned short* arow = Hall;
      if (avalid) arow = Hall + (size_t)(hb + entry) * DFF;
      const unsigned short* drow = W + (size_t)(n0 + sr) * DFF;

      const int lane = tid & 63;
      const int wm = ((tid >> 6) & 1) * 32;
      const int wn = ((tid >> 7) & 1) * 32;
      const int lr = lane & 15, qd = lane >> 4;

      const f32x4 z4 = {0.f, 0.f, 0.f, 0.f};
      f32x4 acc[2][2];
      #pragma unroll
      for (int i = 0; i < 2; ++i)
        #pragma unroll
        for (int j = 0; j < 2; ++j) acc[i][j] = z4;

      for (int k0 = 0; k0 < DFF; k0 += 64) {
        us8 av0 = {0,0,0,0,0,0,0,0}, av1 = {0,0,0,0,0,0,0,0};
        if (avalid) {
          av0 = *(const us8*)(arow + k0 + sc);
          av1 = *(const us8*)(arow + k0 + sc + 8);
        }
        us8 dv0 = *(const us8*)(drow + k0 + sc);
        us8 dv1 = *(const us8*)(drow + k0 + sc + 8);
        __syncthreads();
        *(us8*)&SA[sr][sc] = av0; *(us8*)&SA[sr][sc + 8] = av1;
        *(us8*)&SB[sr][sc] = dv0; *(us8*)&SB[sr][sc + 8] = dv1;
        __syncthreads();
        #pragma unroll
        for (int ks = 0; ks < 2; ++ks) {
          const int kk = ks * 32 + qd * 8;
          bf16x8 a0 = *(const bf16x8*)&SA[wm      + lr][kk];
          bf16x8 a1 = *(const bf16x8*)&SA[wm + 16 + lr][kk];
          bf16x8 b0 = *(const bf16x8*)&SB[wn      + lr][kk];
          bf16x8 b1 = *(const bf16x8*)&SB[wn + 16 + lr][kk];
          acc[0][0] = MFMA(a0, b0, acc[0][0]);
          acc[0][1] = MFMA(a0, b1, acc[0][1]);
          acc[1][0] = MFMA(a1, b0, acc[1][0]);
          acc[1][1] = MFMA(a1, b1, acc[1][1]);
        }
      }

      #pragma unroll
      for (int sm = 0; sm < 2; ++sm)
        #pragma unroll
        for (int sn = 0; sn < 2; ++sn) {
          const int col = n0 + wn + sn * 16 + lr;
          #pragma unroll
          for (int r = 0; r < 4; ++r) {
            const int ent = mt * 64 + wm + sm * 16 + qd * 4 + r;
            if (ent < cnt) {
              float v = acc[sm][sn][r];
              if (z == 0) {
                out[(size_t)ent * DM + col] = v;          // plain store
              } else {
                const float g = wgt[(z - 1) * T_TOK + ent];
                ro[(size_t)(rb + ent) * DM + col] = g * v; // gated, plain store
              }
            }
          }
        }
      __syncthreads();
    }
  }
  if (mode == 0) gg.sync();

  // ================= Phase E: compose out += sum_k ro[slot(t,k)] ===========
  if (mode == 0 || mode == 5) {
    if (tid == 0) {
      int s = 0;
      for (int e = 0; e < NE; ++e) { rbase[e] = s; s += counts[e]; }
    }
    __syncthreads();
    for (int u4 = gtid; u4 < T_TOK * (DM / 4); u4 += T) {
      const int t = u4 >> 7, q = u4 & 127;
      float4 o = ((const float4*)out)[(size_t)t * 128 + q];
      #pragma unroll
      for (int k = 0; k < 3; ++k) {
        const int dec = tokslot[t * 3 + k];
        const int row = rbase[dec >> 16] + (dec & 0xffff);
        float4 r = ((const float4*)ro)[(size_t)row * 128 + q];
        o.x += r.x; o.y += r.y; o.z += r.z; o.w += r.w;
      }
      ((float4*)out)[(size_t)t * 128 + q] = o;
    }
  }
}

// ---------------------------------------------------------------------------
extern "C" void kernel_launch(void* const* d_in, const int* in_sizes, int n_in,
                              void* d_out, int out_size, void* d_ws, size_t ws_size,
                              hipStream_t stream) {
  const float* x    = (const float*)d_in[0];
  const float* gw   = (const float*)d_in[1];
  const float* bias = (const float*)d_in[2];
  const float* sgu  = (const float*)d_in[3];
  const float* sdn  = (const float*)d_in[4];
  const float* egu  = (const float*)d_in[5];
  const float* edn  = (const float*)d_in[6];
  float* out = (float*)d_out;

  // workspace layout (bytes, all 64-aligned)
  char* ws = (char*)d_ws;
  int*            counts  = (int*)(ws + 0);         // 16 ints
  int*            list    = (int*)(ws + 64);        // 16*2048 ints
  float*          wgt     = (float*)(ws + 131136);  // 16*2048 floats
  int*            tokslot = (int*)(ws + 262208);    // 2048*3 ints (24576 B)
  unsigned short* Hall    = (unsigned short*)(ws + 286784);   // 8192*512 bf16
  float*          ro      = (float*)(ws + 8675392);           // 6144*512 fp32
  unsigned short* xb      = (unsigned short*)(ws + 21258304);
  unsigned short* sgub    = (unsigned short*)(ws + 23355456);
  unsigned short* sdnb    = (unsigned short*)(ws + 24404032);
  unsigned short* egub    = (unsigned short*)(ws + 24928320);
  unsigned short* ednb    = (unsigned short*)(ws + 41705536);
  const size_t need = 50094144;
  if (ws_size < need) return;

  // host-side queries run at capture time only (graph replay skips them)
  int dev = 0; hipGetDevice(&dev);
  int coop = 0;
  hipDeviceGetAttribute(&coop, hipDeviceAttributeCooperativeLaunch, dev);
  int nbpm = 0;
  hipError_t oe = hipOccupancyMaxActiveBlocksPerMultiprocessor(&nbpm, moe_kernel, 256, 0);
  if (oe != hipSuccess || nbpm < 1) nbpm = 0;

  if (coop && nbpm >= 1) {
    int blk = nbpm > 4 ? 4 : nbpm;
    int grid = blk * 256;           // 256 CUs on MI355X
    if (grid > 1024) grid = 1024;
    int mode0 = 0;
    void* args[] = {(void*)&x, (void*)&gw, (void*)&bias, (void*)&sgu, (void*)&sdn,
                    (void*)&egu, (void*)&edn, (void*)&counts, (void*)&list,
                    (void*)&wgt, (void*)&tokslot, (void*)&xb, (void*)&sgub,
                    (void*)&sdnb, (void*)&egub, (void*)&ednb, (void*)&Hall,
                    (void*)&ro, (void*)&out, (void*)&mode0};
    hipLaunchCooperativeKernel((const void*)moe_kernel, dim3(grid), dim3(256),
                               args, 0, stream);
  } else {
    // fallback: phases as separate launches (kernel boundaries = grid syncs)
    moe_kernel<<<2048, 256, 0, stream>>>(x, gw, bias, sgu, sdn, egu, edn,
        counts, list, wgt, tokslot, xb, sgub, sdnb, egub, ednb, Hall, ro, out, 1);
    moe_kernel<<< 512, 256, 0, stream>>>(x, gw, bias, sgu, sdn, egu, edn,
        counts, list, wgt, tokslot, xb, sgub, sdnb, egub, ednb, Hall, ro, out, 2);
    moe_kernel<<<1088, 256, 0, stream>>>(x, gw, bias, sgu, sdn, egu, edn,
        counts, list, wgt, tokslot, xb, sgub, sdnb, egub, ednb, Hall, ro, out, 3);
    moe_kernel<<<1088, 256, 0, stream>>>(x, gw, bias, sgu, sdn, egu, edn,
        counts, list, wgt, tokslot, xb, sgub, sdnb, egub, ednb, Hall, ro, out, 4);
    moe_kernel<<<1024, 256, 0, stream>>>(x, gw, bias, sgu, sdn, egu, edn,
        counts, list, wgt, tokslot, xb, sgub, sdnb, egub, ednb, Hall, ro, out, 5);
  }
}

// Round 8
// 168.980 us; speedup vs baseline: 3.0730x; 3.0730x over previous
//
#include <hip/hip_runtime.h>

#define T_TOK 2048
#define DM    512
#define DFF   512
#define NE    16

typedef __attribute__((ext_vector_type(8))) short bf16x8;
typedef __attribute__((ext_vector_type(4))) float f32x4;
typedef __attribute__((ext_vector_type(8))) unsigned short us8;

__device__ __forceinline__ unsigned short f2bf(float f) {
  unsigned int u = __float_as_uint(f);
  u += 0x7fffu + ((u >> 16) & 1u);   // round-to-nearest-even
  return (unsigned short)(u >> 16);
}

// async global->LDS DMA, 16 B per lane; lds base must be wave-uniform
__device__ __forceinline__ void dma16(const unsigned short* g, unsigned short* l) {
  __builtin_amdgcn_global_load_lds(
      (const __attribute__((address_space(1))) unsigned int*)g,
      (__attribute__((address_space(3))) unsigned int*)l, 16, 0, 0);
}

// XOR-swizzled LDS tile: 64 rows x 64 bf16 (128 B/row), chunk c of row r
// stored at slot c ^ (r & 7). DMA windows (1024 B) stay contiguous; readers
// get 2-way bank aliasing (free, m136).
#define LDSOFF(row, chunk) ((((row) << 7) + ((((chunk) ^ ((row) & 7))) << 4)))

#define MFMA(a,b,c) __builtin_amdgcn_mfma_f32_16x16x32_bf16((a),(b),(c),0,0,0)

// ---------------- prep: blocks 0..511 router, 512+ convert + zero out ------
__global__ __launch_bounds__(256) void prep_kernel(
    const float* __restrict__ x, const float* __restrict__ gw,
    const float* __restrict__ bias, int* __restrict__ counts,
    int* __restrict__ list, float* __restrict__ wgt,
    const float* __restrict__ sgu, const float* __restrict__ sdn,
    const float* __restrict__ egu, const float* __restrict__ edn,
    unsigned short* __restrict__ xb,   unsigned short* __restrict__ sgub,
    unsigned short* __restrict__ sdnb, unsigned short* __restrict__ egub,
    unsigned short* __restrict__ ednb, float* __restrict__ out)
{
  const int tid = threadIdx.x;
  if (blockIdx.x >= 512) {
    // zero out (2048*512 fp32 = 262144 float4) + convert fp32->bf16
    const int cb = blockIdx.x - 512;           // 0..7039
    const int ct = cb * 256 + tid;
    const int CT = 7040 * 256;
    const float4 z4 = {0.f, 0.f, 0.f, 0.f};
    for (int i = ct; i < 262144; i += CT) ((float4*)out)[i] = z4;
    // groups of 8: x 131072 | sgu 65536 | sdn 32768 | egu 1048576 | edn 524288
    int g = ct;
    const float* s; unsigned short* d; int l;
    if      (g <  131072) { s = x;   d = xb;   l = g;           }
    else if (g <  196608) { s = sgu; d = sgub; l = g -  131072; }
    else if (g <  229376) { s = sdn; d = sdnb; l = g -  196608; }
    else if (g < 1277952) { s = egu; d = egub; l = g -  229376; }
    else                  { s = edn; d = ednb; l = g - 1277952; }
    const float* p = s + (size_t)l * 8;
    float4 v0 = *(const float4*)p;
    float4 v1 = *(const float4*)(p + 4);
    us8 o;
    o[0]=f2bf(v0.x); o[1]=f2bf(v0.y); o[2]=f2bf(v0.z); o[3]=f2bf(v0.w);
    o[4]=f2bf(v1.x); o[5]=f2bf(v1.y); o[6]=f2bf(v1.z); o[7]=f2bf(v1.w);
    *(us8*)(d + (size_t)l * 8) = o;
    return;
  }

  // ---- router: one token per wave ----
  __shared__ float lg[4][16];
  __shared__ int bcnt[16], bbase[16];
  __shared__ int sel_s[4][3], pos_s[4][3];
  __shared__ float g_s[4][3];

  const int w = tid >> 6, lane = tid & 63;
  if (tid < 16) bcnt[tid] = 0;
  const int tok = blockIdx.x * 4 + w;
  const int e = lane & 15, part = lane >> 4;

  const float* xr = x + (size_t)tok * DM + part * 128;
  const float* wr = gw + (size_t)e * DM + part * 128;
  float acc = 0.f;
  #pragma unroll 8
  for (int i = 0; i < 128; i += 4) {
    float4 xv = *(const float4*)(xr + i);
    float4 wv = *(const float4*)(wr + i);
    acc += xv.x*wv.x + xv.y*wv.y + xv.z*wv.z + xv.w*wv.w;
  }
  acc += __shfl_xor(acc, 16);
  acc += __shfl_xor(acc, 32);
  if (lane < 16) lg[w][lane] = 1.f / (1.f + __expf(-acc));  // affinity
  __syncthreads();

  if (tid < 4) {
    float aff[16], sc[16];
    #pragma unroll
    for (int i = 0; i < 16; ++i) { aff[i] = lg[tid][i]; sc[i] = aff[i] + bias[i]; }
    int sel[3]; float sa[3]; float sum = 0.f;
    #pragma unroll
    for (int k = 0; k < 3; ++k) {
      float best = -1e30f; int bi = 0;
      for (int i = 0; i < 16; ++i) {
        bool used = false;
        for (int j = 0; j < k; ++j) used |= (sel[j] == i);
        if (!used && sc[i] > best) { best = sc[i]; bi = i; }
      }
      sel[k] = bi; sa[k] = aff[bi]; sum += aff[bi];
    }
    float inv = 1.f / (sum + 1e-9f);
    #pragma unroll
    for (int k = 0; k < 3; ++k) {
      int p = atomicAdd(&bcnt[sel[k]], 1);
      sel_s[tid][k] = sel[k]; pos_s[tid][k] = p; g_s[tid][k] = sa[k] * inv;
    }
  }
  __syncthreads();
  if (tid < 16) bbase[tid] = atomicAdd(&counts[tid], bcnt[tid]);
  __syncthreads();
  if (tid < 4) {
    #pragma unroll
    for (int k = 0; k < 3; ++k) {
      int E = sel_s[tid][k];
      int p = bbase[E] + pos_s[tid][k];
      list[E * T_TOK + p] = blockIdx.x * 4 + tid;
      wgt [E * T_TOK + p] = g_s[tid][k];
    }
  }
}

// ---------------- GEMM1: 64 tok x 64 Hcols per block, DMA-staged LDS -------
// z=0 shared expert, z>=1 routed expert z-1. Fused silu(g)*u -> Hall (bf16).
__global__ __launch_bounds__(256, 4) void gemm1_fused(
    const unsigned short* __restrict__ X, const unsigned short* __restrict__ Wsh,
    const unsigned short* __restrict__ Wex, unsigned short* __restrict__ Hall,
    const int* __restrict__ counts, const int* __restrict__ list)
{
  __shared__ unsigned short SA[64][64];
  __shared__ unsigned short SG[64][64];
  __shared__ unsigned short SU[64][64];

  const int n0 = blockIdx.x * 64;           // H col block
  const int mt = blockIdx.y, z = blockIdx.z;
  int cnt, hb; const unsigned short* W;
  if (z == 0) { cnt = T_TOK; hb = 0; W = Wsh; }
  else {
    const int e = z - 1;
    cnt = counts[e];
    if (mt * 64 >= cnt) return;
    hb = T_TOK;
    for (int i = 0; i < e; ++i) hb += counts[i];
    W = Wex + (size_t)e * (2 * DFF * DM);
  }

  const int tid = threadIdx.x, w = tid >> 6, lane = tid & 63;
  // staging: wave w owns rows 16w..16w+15 via 2 DMA windows of 8 rows
  const int r0 = w * 16 + (lane >> 3);       // q=0 row; q=1 row = r0+8
  const int cch = (lane & 7) ^ (r0 & 7);     // src chunk (same for both windows)
  // A rows (token-gathered, clamped)
  const unsigned short* ga[2];
  #pragma unroll
  for (int q = 0; q < 2; ++q) {
    int ra = mt * 64 + r0 + q * 8;
    int rc = ra < cnt ? ra : cnt - 1;
    int tokr = (z == 0) ? rc : list[(z - 1) * T_TOK + rc];
    ga[q] = X + (size_t)tokr * DM + cch * 8;
  }
  const unsigned short *gg[2], *gu[2];
  #pragma unroll
  for (int q = 0; q < 2; ++q) {
    int rb = n0 + r0 + q * 8;
    gg[q] = W + (size_t)rb * DM + cch * 8;
    gu[q] = W + (size_t)(DFF + rb) * DM + cch * 8;
  }
  unsigned short* const lA0 = &SA[w * 16][0];
  unsigned short* const lA1 = &SA[w * 16 + 8][0];
  unsigned short* const lG0 = &SG[w * 16][0];
  unsigned short* const lG1 = &SG[w * 16 + 8][0];
  unsigned short* const lU0 = &SU[w * 16][0];
  unsigned short* const lU1 = &SU[w * 16 + 8][0];

  const int wm = ((tid >> 6) & 1) * 32;
  const int wn = ((tid >> 7) & 1) * 32;
  const int lr = lane & 15, qd = lane >> 4;
  const char* const sa = (const char*)SA;
  const char* const sg = (const char*)SG;
  const char* const su = (const char*)SU;

  const f32x4 z4 = {0.f, 0.f, 0.f, 0.f};
  f32x4 accg[2][2], accu[2][2];
  #pragma unroll
  for (int i = 0; i < 2; ++i)
    #pragma unroll
    for (int j = 0; j < 2; ++j) { accg[i][j] = z4; accu[i][j] = z4; }

  for (int k0 = 0; k0 < DM; k0 += 64) {
    __syncthreads();                          // prior reads done
    dma16(ga[0] + k0, lA0); dma16(ga[1] + k0, lA1);
    dma16(gg[0] + k0, lG0); dma16(gg[1] + k0, lG1);
    dma16(gu[0] + k0, lU0); dma16(gu[1] + k0, lU1);
    __syncthreads();                          // vmcnt(0) drain: tiles ready
    #pragma unroll
    for (int ks = 0; ks < 2; ++ks) {
      const int ch = ks * 4 + qd;             // 16B chunk index in row
      bf16x8 a0 = *(const bf16x8*)(sa + LDSOFF(wm      + lr, ch));
      bf16x8 a1 = *(const bf16x8*)(sa + LDSOFF(wm + 16 + lr, ch));
      bf16x8 g0 = *(const bf16x8*)(sg + LDSOFF(wn      + lr, ch));
      bf16x8 g1 = *(const bf16x8*)(sg + LDSOFF(wn + 16 + lr, ch));
      bf16x8 u0 = *(const bf16x8*)(su + LDSOFF(wn      + lr, ch));
      bf16x8 u1 = *(const bf16x8*)(su + LDSOFF(wn + 16 + lr, ch));
      accg[0][0] = MFMA(a0, g0, accg[0][0]);
      accg[0][1] = MFMA(a0, g1, accg[0][1]);
      accg[1][0] = MFMA(a1, g0, accg[1][0]);
      accg[1][1] = MFMA(a1, g1, accg[1][1]);
      accu[0][0] = MFMA(a0, u0, accu[0][0]);
      accu[0][1] = MFMA(a0, u1, accu[0][1]);
      accu[1][0] = MFMA(a1, u0, accu[1][0]);
      accu[1][1] = MFMA(a1, u1, accu[1][1]);
    }
  }

  #pragma unroll
  for (int sm = 0; sm < 2; ++sm)
    #pragma unroll
    for (int sn = 0; sn < 2; ++sn) {
      const int col = n0 + wn + sn * 16 + lr;
      #pragma unroll
      for (int r = 0; r < 4; ++r) {
        const int ent = mt * 64 + wm + sm * 16 + qd * 4 + r;
        if (ent < cnt) {
          float g = accg[sm][sn][r];
          float u = accu[sm][sn][r];
          float h = (g / (1.f + __expf(-g))) * u;   // silu(g)*u
          Hall[(size_t)(hb + ent) * DFF + col] = f2bf(h);
        }
      }
    }
}

// ---------------- GEMM2: 64 tok x 64 out-cols per block, DMA-staged --------
__global__ __launch_bounds__(256, 4) void gemm2_fused(
    const unsigned short* __restrict__ Hall, const unsigned short* __restrict__ Wsh,
    const unsigned short* __restrict__ Wex, float* __restrict__ out,
    const int* __restrict__ counts, const int* __restrict__ list,
    const float* __restrict__ wgt)
{
  __shared__ unsigned short SA[64][64];
  __shared__ unsigned short SB[64][64];

  const int n0 = blockIdx.x * 64;           // out col block
  const int mt = blockIdx.y, z = blockIdx.z;
  int cnt, hb; const unsigned short* W;
  if (z == 0) { cnt = T_TOK; hb = 0; W = Wsh; }
  else {
    const int e = z - 1;
    cnt = counts[e];
    if (mt * 64 >= cnt) return;
    hb = T_TOK;
    for (int i = 0; i < e; ++i) hb += counts[i];
    W = Wex + (size_t)e * (DM * DFF);
  }

  const int tid = threadIdx.x, w = tid >> 6, lane = tid & 63;
  const int r0 = w * 16 + (lane >> 3);
  const int cch = (lane & 7) ^ (r0 & 7);
  const unsigned short* ga[2];
  #pragma unroll
  for (int q = 0; q < 2; ++q) {
    int ra = mt * 64 + r0 + q * 8;
    int rc = ra < cnt ? ra : cnt - 1;
    ga[q] = Hall + (size_t)(hb + rc) * DFF + cch * 8;
  }
  const unsigned short* gb[2];
  #pragma unroll
  for (int q = 0; q < 2; ++q)
    gb[q] = W + (size_t)(n0 + r0 + q * 8) * DFF + cch * 8;
  unsigned short* const lA0 = &SA[w * 16][0];
  unsigned short* const lA1 = &SA[w * 16 + 8][0];
  unsigned short* const lB0 = &SB[w * 16][0];
  unsigned short* const lB1 = &SB[w * 16 + 8][0];

  const int wm = ((tid >> 6) & 1) * 32;
  const int wn = ((tid >> 7) & 1) * 32;
  const int lr = lane & 15, qd = lane >> 4;
  const char* const sa = (const char*)SA;
  const char* const sb = (const char*)SB;

  const f32x4 z4 = {0.f, 0.f, 0.f, 0.f};
  f32x4 acc[2][2];
  #pragma unroll
  for (int i = 0; i < 2; ++i)
    #pragma unroll
    for (int j = 0; j < 2; ++j) acc[i][j] = z4;

  for (int k0 = 0; k0 < DFF; k0 += 64) {
    __syncthreads();
    dma16(ga[0] + k0, lA0); dma16(ga[1] + k0, lA1);
    dma16(gb[0] + k0, lB0); dma16(gb[1] + k0, lB1);
    __syncthreads();
    #pragma unroll
    for (int ks = 0; ks < 2; ++ks) {
      const int ch = ks * 4 + qd;
      bf16x8 a0 = *(const bf16x8*)(sa + LDSOFF(wm      + lr, ch));
      bf16x8 a1 = *(const bf16x8*)(sa + LDSOFF(wm + 16 + lr, ch));
      bf16x8 b0 = *(const bf16x8*)(sb + LDSOFF(wn      + lr, ch));
      bf16x8 b1 = *(const bf16x8*)(sb + LDSOFF(wn + 16 + lr, ch));
      acc[0][0] = MFMA(a0, b0, acc[0][0]);
      acc[0][1] = MFMA(a0, b1, acc[0][1]);
      acc[1][0] = MFMA(a1, b0, acc[1][0]);
      acc[1][1] = MFMA(a1, b1, acc[1][1]);
    }
  }

  #pragma unroll
  for (int sm = 0; sm < 2; ++sm)
    #pragma unroll
    for (int sn = 0; sn < 2; ++sn) {
      const int col = n0 + wn + sn * 16 + lr;
      #pragma unroll
      for (int r = 0; r < 4; ++r) {
        const int ent = mt * 64 + wm + sm * 16 + qd * 4 + r;
        if (ent < cnt) {
          float v = acc[sm][sn][r];
          if (z == 0) {
            atomicAdd(out + (size_t)ent * DM + col, v);
          } else {
            const int   tok = list[(z - 1) * T_TOK + ent];
            const float g   = wgt [(z - 1) * T_TOK + ent];
            atomicAdd(out + (size_t)tok * DM + col, g * v);
          }
        }
      }
    }
}

// ---------------------------------------------------------------------------
extern "C" void kernel_launch(void* const* d_in, const int* in_sizes, int n_in,
                              void* d_out, int out_size, void* d_ws, size_t ws_size,
                              hipStream_t stream) {
  const float* x    = (const float*)d_in[0];
  const float* gw   = (const float*)d_in[1];
  const float* bias = (const float*)d_in[2];
  const float* sgu  = (const float*)d_in[3];
  const float* sdn  = (const float*)d_in[4];
  const float* egu  = (const float*)d_in[5];
  const float* edn  = (const float*)d_in[6];
  float* out = (float*)d_out;

  // workspace layout (bytes)
  char* ws = (char*)d_ws;
  int*            counts = (int*)(ws + 0);        // 16 ints
  int*            list   = (int*)(ws + 64);       // 16*2048 ints
  float*          wgt    = (float*)(ws + 131136); // 16*2048 floats
  unsigned short* Hall   = (unsigned short*)(ws + 262208); // 8192*512 bf16
  unsigned short* xb     = (unsigned short*)(ws + 8650816);
  unsigned short* sgub   = (unsigned short*)(ws + 10747968);
  unsigned short* sdnb   = (unsigned short*)(ws + 11796544);
  unsigned short* egub   = (unsigned short*)(ws + 12320832);
  unsigned short* ednb   = (unsigned short*)(ws + 29098048);
  const size_t need = 37486656;
  if (ws_size < need) return;

  hipMemsetAsync(counts, 0, 64, stream);
  prep_kernel<<<512 + 7040, 256, 0, stream>>>(
      x, gw, bias, counts, list, wgt, sgu, sdn, egu, edn,
      xb, sgub, sdnb, egub, ednb, out);
  gemm1_fused<<<dim3(8, 32, NE + 1), 256, 0, stream>>>(xb, sgub, egub, Hall, counts, list);
  gemm2_fused<<<dim3(8, 32, NE + 1), 256, 0, stream>>>(Hall, sdnb, ednb, out, counts, list, wgt);
}

// Round 9
// 168.483 us; speedup vs baseline: 3.0821x; 1.0030x over previous
//
#include <hip/hip_runtime.h>

#define T_TOK 2048
#define DM    512
#define DFF   512
#define NE    16

typedef __attribute__((ext_vector_type(8))) short bf16x8;
typedef __attribute__((ext_vector_type(4))) float f32x4;
typedef __attribute__((ext_vector_type(8))) unsigned short us8;

__device__ __forceinline__ unsigned short f2bf(float f) {
  unsigned int u = __float_as_uint(f);
  u += 0x7fffu + ((u >> 16) & 1u);   // round-to-nearest-even
  return (unsigned short)(u >> 16);
}

// async global->LDS DMA, 16 B per lane; lds base must be wave-uniform
__device__ __forceinline__ void dma16(const unsigned short* g, unsigned short* l) {
  __builtin_amdgcn_global_load_lds(
      (const __attribute__((address_space(1))) unsigned int*)g,
      (__attribute__((address_space(3))) unsigned int*)l, 16, 0, 0);
}

// XOR-swizzled LDS tile: 64 rows x 64 bf16 (128 B/row), chunk c of row r
// stored at slot c ^ (r & 7). DMA windows (1024 B) stay contiguous; readers
// get 2-way bank aliasing (free, m136).
#define LDSOFF(row, chunk) ((((row) << 7) + ((((chunk) ^ ((row) & 7))) << 4)))

#define MFMA(a,b,c) __builtin_amdgcn_mfma_f32_16x16x32_bf16((a),(b),(c),0,0,0)

// ---------------- prep: blocks 0..511 router, 512+ convert + zero out ------
__global__ __launch_bounds__(256) void prep_kernel(
    const float* __restrict__ x, const float* __restrict__ gw,
    const float* __restrict__ bias, int* __restrict__ counts,
    int* __restrict__ list, float* __restrict__ wgt,
    const float* __restrict__ sgu, const float* __restrict__ sdn,
    const float* __restrict__ egu, const float* __restrict__ edn,
    unsigned short* __restrict__ xb,   unsigned short* __restrict__ sgub,
    unsigned short* __restrict__ sdnb, unsigned short* __restrict__ egub,
    unsigned short* __restrict__ ednb, float* __restrict__ out)
{
  const int tid = threadIdx.x;
  if (blockIdx.x >= 512) {
    // zero out (2048*512 fp32 = 262144 float4) + convert fp32->bf16
    const int cb = blockIdx.x - 512;           // 0..7039
    const int ct = cb * 256 + tid;
    const int CT = 7040 * 256;
    const float4 z4 = {0.f, 0.f, 0.f, 0.f};
    for (int i = ct; i < 262144; i += CT) ((float4*)out)[i] = z4;
    // groups of 8: x 131072 | sgu 65536 | sdn 32768 | egu 1048576 | edn 524288
    int g = ct;
    const float* s; unsigned short* d; int l;
    if      (g <  131072) { s = x;   d = xb;   l = g;           }
    else if (g <  196608) { s = sgu; d = sgub; l = g -  131072; }
    else if (g <  229376) { s = sdn; d = sdnb; l = g -  196608; }
    else if (g < 1277952) { s = egu; d = egub; l = g -  229376; }
    else                  { s = edn; d = ednb; l = g - 1277952; }
    const float* p = s + (size_t)l * 8;
    float4 v0 = *(const float4*)p;
    float4 v1 = *(const float4*)(p + 4);
    us8 o;
    o[0]=f2bf(v0.x); o[1]=f2bf(v0.y); o[2]=f2bf(v0.z); o[3]=f2bf(v0.w);
    o[4]=f2bf(v1.x); o[5]=f2bf(v1.y); o[6]=f2bf(v1.z); o[7]=f2bf(v1.w);
    *(us8*)(d + (size_t)l * 8) = o;
    return;
  }

  // ---- router: one token per wave ----
  __shared__ float lg[4][16];
  __shared__ int bcnt[16], bbase[16];
  __shared__ int sel_s[4][3], pos_s[4][3];
  __shared__ float g_s[4][3];

  const int w = tid >> 6, lane = tid & 63;
  if (tid < 16) bcnt[tid] = 0;
  const int tok = blockIdx.x * 4 + w;
  const int e = lane & 15, part = lane >> 4;

  const float* xr = x + (size_t)tok * DM + part * 128;
  const float* wr = gw + (size_t)e * DM + part * 128;
  float acc = 0.f;
  #pragma unroll 8
  for (int i = 0; i < 128; i += 4) {
    float4 xv = *(const float4*)(xr + i);
    float4 wv = *(const float4*)(wr + i);
    acc += xv.x*wv.x + xv.y*wv.y + xv.z*wv.z + xv.w*wv.w;
  }
  acc += __shfl_xor(acc, 16);
  acc += __shfl_xor(acc, 32);
  if (lane < 16) lg[w][lane] = 1.f / (1.f + __expf(-acc));  // affinity
  __syncthreads();

  if (tid < 4) {
    float aff[16], sc[16];
    #pragma unroll
    for (int i = 0; i < 16; ++i) { aff[i] = lg[tid][i]; sc[i] = aff[i] + bias[i]; }
    int sel[3]; float sa[3]; float sum = 0.f;
    #pragma unroll
    for (int k = 0; k < 3; ++k) {
      float best = -1e30f; int bi = 0;
      for (int i = 0; i < 16; ++i) {
        bool used = false;
        for (int j = 0; j < k; ++j) used |= (sel[j] == i);
        if (!used && sc[i] > best) { best = sc[i]; bi = i; }
      }
      sel[k] = bi; sa[k] = aff[bi]; sum += aff[bi];
    }
    float inv = 1.f / (sum + 1e-9f);
    #pragma unroll
    for (int k = 0; k < 3; ++k) {
      int p = atomicAdd(&bcnt[sel[k]], 1);
      sel_s[tid][k] = sel[k]; pos_s[tid][k] = p; g_s[tid][k] = sa[k] * inv;
    }
  }
  __syncthreads();
  if (tid < 16) bbase[tid] = atomicAdd(&counts[tid], bcnt[tid]);
  __syncthreads();
  if (tid < 4) {
    #pragma unroll
    for (int k = 0; k < 3; ++k) {
      int E = sel_s[tid][k];
      int p = bbase[E] + pos_s[tid][k];
      list[E * T_TOK + p] = blockIdx.x * 4 + tid;
      wgt [E * T_TOK + p] = g_s[tid][k];
    }
  }
}

// ---------------- GEMM1: 64x64 tiles, double-buffered DMA staging ----------
// z=0 shared expert, z>=1 routed expert z-1. Fused silu(g)*u -> Hall (bf16).
__global__ __launch_bounds__(256, 3) void gemm1_fused(
    const unsigned short* __restrict__ X, const unsigned short* __restrict__ Wsh,
    const unsigned short* __restrict__ Wex, unsigned short* __restrict__ Hall,
    const int* __restrict__ counts, const int* __restrict__ list)
{
  __shared__ unsigned short SA[2][64][64];
  __shared__ unsigned short SG[2][64][64];
  __shared__ unsigned short SU[2][64][64];

  const int n0 = blockIdx.x * 64;           // H col block
  const int mt = blockIdx.y, z = blockIdx.z;
  int cnt, hb; const unsigned short* W;
  if (z == 0) { cnt = T_TOK; hb = 0; W = Wsh; }
  else {
    const int e = z - 1;
    cnt = counts[e];
    if (mt * 64 >= cnt) return;
    hb = T_TOK;
    for (int i = 0; i < e; ++i) hb += counts[i];
    W = Wex + (size_t)e * (2 * DFF * DM);
  }

  const int tid = threadIdx.x, w = tid >> 6, lane = tid & 63;
  // staging: wave w owns rows 16w..16w+15 via 2 DMA windows of 8 rows
  const int r0 = w * 16 + (lane >> 3);       // q=0 row; q=1 row = r0+8
  const int cch = (lane & 7) ^ (r0 & 7);     // src chunk (XOR swizzle)
  const unsigned short* ga[2];
  #pragma unroll
  for (int q = 0; q < 2; ++q) {
    int ra = mt * 64 + r0 + q * 8;
    int rc = ra < cnt ? ra : cnt - 1;
    int tokr = (z == 0) ? rc : list[(z - 1) * T_TOK + rc];
    ga[q] = X + (size_t)tokr * DM + cch * 8;
  }
  const unsigned short *gg[2], *gu[2];
  #pragma unroll
  for (int q = 0; q < 2; ++q) {
    int rb = n0 + r0 + q * 8;
    gg[q] = W + (size_t)rb * DM + cch * 8;
    gu[q] = W + (size_t)(DFF + rb) * DM + cch * 8;
  }
  unsigned short* lA[2][2]; unsigned short* lG[2][2]; unsigned short* lU[2][2];
  #pragma unroll
  for (int b = 0; b < 2; ++b)
    #pragma unroll
    for (int q = 0; q < 2; ++q) {
      lA[b][q] = &SA[b][w * 16 + q * 8][0];
      lG[b][q] = &SG[b][w * 16 + q * 8][0];
      lU[b][q] = &SU[b][w * 16 + q * 8][0];
    }

  const int wm = ((tid >> 6) & 1) * 32;
  const int wn = ((tid >> 7) & 1) * 32;
  const int lr = lane & 15, qd = lane >> 4;
  const char* const sa = (const char*)SA;
  const char* const sg = (const char*)SG;
  const char* const su = (const char*)SU;

  const f32x4 z4 = {0.f, 0.f, 0.f, 0.f};
  f32x4 accg[2][2], accu[2][2];
  #pragma unroll
  for (int i = 0; i < 2; ++i)
    #pragma unroll
    for (int j = 0; j < 2; ++j) { accg[i][j] = z4; accu[i][j] = z4; }

  // prologue: stage tile 0 into buf 0
  #pragma unroll
  for (int q = 0; q < 2; ++q) {
    dma16(ga[q], lA[0][q]); dma16(gg[q], lG[0][q]); dma16(gu[q], lU[0][q]);
  }

  #pragma unroll
  for (int i = 0; i < DM / 64; ++i) {
    const int b = i & 1;
    __syncthreads();                         // buf b ready (drains all DMA)
    if (i + 1 < DM / 64) {
      const int k1 = (i + 1) * 64, nb = b ^ 1;
      #pragma unroll
      for (int q = 0; q < 2; ++q) {
        dma16(ga[q] + k1, lA[nb][q]);
        dma16(gg[q] + k1, lG[nb][q]);
        dma16(gu[q] + k1, lU[nb][q]);
      }
    }
    const int bo = b * 8192;                 // buffer byte offset
    #pragma unroll
    for (int ks = 0; ks < 2; ++ks) {
      const int ch = ks * 4 + qd;            // 16B chunk index in row
      bf16x8 a0 = *(const bf16x8*)(sa + bo + LDSOFF(wm      + lr, ch));
      bf16x8 a1 = *(const bf16x8*)(sa + bo + LDSOFF(wm + 16 + lr, ch));
      bf16x8 g0 = *(const bf16x8*)(sg + bo + LDSOFF(wn      + lr, ch));
      bf16x8 g1 = *(const bf16x8*)(sg + bo + LDSOFF(wn + 16 + lr, ch));
      bf16x8 u0 = *(const bf16x8*)(su + bo + LDSOFF(wn      + lr, ch));
      bf16x8 u1 = *(const bf16x8*)(su + bo + LDSOFF(wn + 16 + lr, ch));
      accg[0][0] = MFMA(a0, g0, accg[0][0]);
      accg[0][1] = MFMA(a0, g1, accg[0][1]);
      accg[1][0] = MFMA(a1, g0, accg[1][0]);
      accg[1][1] = MFMA(a1, g1, accg[1][1]);
      accu[0][0] = MFMA(a0, u0, accu[0][0]);
      accu[0][1] = MFMA(a0, u1, accu[0][1]);
      accu[1][0] = MFMA(a1, u0, accu[1][0]);
      accu[1][1] = MFMA(a1, u1, accu[1][1]);
    }
  }

  #pragma unroll
  for (int sm = 0; sm < 2; ++sm)
    #pragma unroll
    for (int sn = 0; sn < 2; ++sn) {
      const int col = n0 + wn + sn * 16 + lr;
      #pragma unroll
      for (int r = 0; r < 4; ++r) {
        const int ent = mt * 64 + wm + sm * 16 + qd * 4 + r;
        if (ent < cnt) {
          float g = accg[sm][sn][r];
          float u = accu[sm][sn][r];
          float h = (g / (1.f + __expf(-g))) * u;   // silu(g)*u
          Hall[(size_t)(hb + ent) * DFF + col] = f2bf(h);
        }
      }
    }
}

// ---------------- GEMM2: 64x64 tiles, double-buffered DMA staging ----------
__global__ __launch_bounds__(256, 4) void gemm2_fused(
    const unsigned short* __restrict__ Hall, const unsigned short* __restrict__ Wsh,
    const unsigned short* __restrict__ Wex, float* __restrict__ out,
    const int* __restrict__ counts, const int* __restrict__ list,
    const float* __restrict__ wgt)
{
  __shared__ unsigned short SA[2][64][64];
  __shared__ unsigned short SB[2][64][64];

  const int n0 = blockIdx.x * 64;           // out col block
  const int mt = blockIdx.y, z = blockIdx.z;
  int cnt, hb; const unsigned short* W;
  if (z == 0) { cnt = T_TOK; hb = 0; W = Wsh; }
  else {
    const int e = z - 1;
    cnt = counts[e];
    if (mt * 64 >= cnt) return;
    hb = T_TOK;
    for (int i = 0; i < e; ++i) hb += counts[i];
    W = Wex + (size_t)e * (DM * DFF);
  }

  const int tid = threadIdx.x, w = tid >> 6, lane = tid & 63;
  const int r0 = w * 16 + (lane >> 3);
  const int cch = (lane & 7) ^ (r0 & 7);
  const unsigned short* ga[2];
  #pragma unroll
  for (int q = 0; q < 2; ++q) {
    int ra = mt * 64 + r0 + q * 8;
    int rc = ra < cnt ? ra : cnt - 1;
    ga[q] = Hall + (size_t)(hb + rc) * DFF + cch * 8;
  }
  const unsigned short* gb[2];
  #pragma unroll
  for (int q = 0; q < 2; ++q)
    gb[q] = W + (size_t)(n0 + r0 + q * 8) * DFF + cch * 8;
  unsigned short* lA[2][2]; unsigned short* lB[2][2];
  #pragma unroll
  for (int b = 0; b < 2; ++b)
    #pragma unroll
    for (int q = 0; q < 2; ++q) {
      lA[b][q] = &SA[b][w * 16 + q * 8][0];
      lB[b][q] = &SB[b][w * 16 + q * 8][0];
    }

  const int wm = ((tid >> 6) & 1) * 32;
  const int wn = ((tid >> 7) & 1) * 32;
  const int lr = lane & 15, qd = lane >> 4;
  const char* const sa = (const char*)SA;
  const char* const sb = (const char*)SB;

  const f32x4 z4 = {0.f, 0.f, 0.f, 0.f};
  f32x4 acc[2][2];
  #pragma unroll
  for (int i = 0; i < 2; ++i)
    #pragma unroll
    for (int j = 0; j < 2; ++j) acc[i][j] = z4;

  #pragma unroll
  for (int q = 0; q < 2; ++q) { dma16(ga[q], lA[0][q]); dma16(gb[q], lB[0][q]); }

  #pragma unroll
  for (int i = 0; i < DFF / 64; ++i) {
    const int b = i & 1;
    __syncthreads();
    if (i + 1 < DFF / 64) {
      const int k1 = (i + 1) * 64, nb = b ^ 1;
      #pragma unroll
      for (int q = 0; q < 2; ++q) {
        dma16(ga[q] + k1, lA[nb][q]);
        dma16(gb[q] + k1, lB[nb][q]);
      }
    }
    const int bo = b * 8192;
    #pragma unroll
    for (int ks = 0; ks < 2; ++ks) {
      const int ch = ks * 4 + qd;
      bf16x8 a0 = *(const bf16x8*)(sa + bo + LDSOFF(wm      + lr, ch));
      bf16x8 a1 = *(const bf16x8*)(sa + bo + LDSOFF(wm + 16 + lr, ch));
      bf16x8 b0 = *(const bf16x8*)(sb + bo + LDSOFF(wn      + lr, ch));
      bf16x8 b1 = *(const bf16x8*)(sb + bo + LDSOFF(wn + 16 + lr, ch));
      acc[0][0] = MFMA(a0, b0, acc[0][0]);
      acc[0][1] = MFMA(a0, b1, acc[0][1]);
      acc[1][0] = MFMA(a1, b0, acc[1][0]);
      acc[1][1] = MFMA(a1, b1, acc[1][1]);
    }
  }

  #pragma unroll
  for (int sm = 0; sm < 2; ++sm)
    #pragma unroll
    for (int sn = 0; sn < 2; ++sn) {
      const int col = n0 + wn + sn * 16 + lr;
      #pragma unroll
      for (int r = 0; r < 4; ++r) {
        const int ent = mt * 64 + wm + sm * 16 + qd * 4 + r;
        if (ent < cnt) {
          float v = acc[sm][sn][r];
          if (z == 0) {
            atomicAdd(out + (size_t)ent * DM + col, v);
          } else {
            const int   tok = list[(z - 1) * T_TOK + ent];
            const float g   = wgt [(z - 1) * T_TOK + ent];
            atomicAdd(out + (size_t)tok * DM + col, g * v);
          }
        }
      }
    }
}

// ---------------------------------------------------------------------------
extern "C" void kernel_launch(void* const* d_in, const int* in_sizes, int n_in,
                              void* d_out, int out_size, void* d_ws, size_t ws_size,
                              hipStream_t stream) {
  const float* x    = (const float*)d_in[0];
  const float* gw   = (const float*)d_in[1];
  const float* bias = (const float*)d_in[2];
  const float* sgu  = (const float*)d_in[3];
  const float* sdn  = (const float*)d_in[4];
  const float* egu  = (const float*)d_in[5];
  const float* edn  = (const float*)d_in[6];
  float* out = (float*)d_out;

  // workspace layout (bytes)
  char* ws = (char*)d_ws;
  int*            counts = (int*)(ws + 0);        // 16 ints
  int*            list   = (int*)(ws + 64);       // 16*2048 ints
  float*          wgt    = (float*)(ws + 131136); // 16*2048 floats
  unsigned short* Hall   = (unsigned short*)(ws + 262208); // 8192*512 bf16
  unsigned short* xb     = (unsigned short*)(ws + 8650816);
  unsigned short* sgub   = (unsigned short*)(ws + 10747968);
  unsigned short* sdnb   = (unsigned short*)(ws + 11796544);
  unsigned short* egub   = (unsigned short*)(ws + 12320832);
  unsigned short* ednb   = (unsigned short*)(ws + 29098048);
  const size_t need = 37486656;
  if (ws_size < need) return;

  hipMemsetAsync(counts, 0, 64, stream);
  prep_kernel<<<512 + 7040, 256, 0, stream>>>(
      x, gw, bias, counts, list, wgt, sgu, sdn, egu, edn,
      xb, sgub, sdnb, egub, ednb, out);
  gemm1_fused<<<dim3(8, 32, NE + 1), 256, 0, stream>>>(xb, sgub, egub, Hall, counts, list);
  gemm2_fused<<<dim3(8, 32, NE + 1), 256, 0, stream>>>(Hall, sdnb, ednb, out, counts, list, wgt);
}